// Round 1
// baseline (1159.561 us; speedup 1.0000x reference)
//
#include <hip/hip_runtime.h>

typedef unsigned int u32;
typedef unsigned long long u64;

#define CAND_MAX 131072u
#define MEMB_MAX 65536u
#define SORT_N   65536u

// Monotone key for signed float ascending order (no NaNs in this problem)
__device__ __forceinline__ u32 fkey32(u32 fb) {
  return (fb & 0x80000000u) ? ~fb : (fb | 0x80000000u);
}

// ---------------- Pass 1: coarse histogram of bits(|g+r|) >> 20 (2048 bins) ----------
__global__ void k_hist(const float4* __restrict__ g, const float4* __restrict__ r,
                       int n4, u32* __restrict__ hist) {
  __shared__ u32 lh[2048];
  for (int i = threadIdx.x; i < 2048; i += blockDim.x) lh[i] = 0;
  __syncthreads();
  int stride = gridDim.x * blockDim.x;
  for (int i = blockIdx.x * blockDim.x + threadIdx.x; i < n4; i += stride) {
    float4 a = g[i]; float4 b = r[i];
    u32 u0 = __float_as_uint(a.x + b.x) & 0x7fffffffu;
    u32 u1 = __float_as_uint(a.y + b.y) & 0x7fffffffu;
    u32 u2 = __float_as_uint(a.z + b.z) & 0x7fffffffu;
    u32 u3 = __float_as_uint(a.w + b.w) & 0x7fffffffu;
    atomicAdd(&lh[u0 >> 20], 1u);
    atomicAdd(&lh[u1 >> 20], 1u);
    atomicAdd(&lh[u2 >> 20], 1u);
    atomicAdd(&lh[u3 >> 20], 1u);
  }
  __syncthreads();
  for (int i = threadIdx.x; i < 2048; i += blockDim.x)
    if (lh[i]) atomicAdd(&hist[i], lh[i]);
}

// ---------------- Pass 2: suffix-scan histogram, find coarse bin ----------
// ctrl[0]=B12 coarse bin, ctrl[1]=a (count strictly above), ctrl[2]=r=k-a
// ctrl[3]=candidate count, ctrl[4]=member count, ctrl[5]=exact T, ctrl[6]=tie idx cutoff
__global__ void __launch_bounds__(1024) k_scan(const u32* __restrict__ hist,
                                               u32* __restrict__ ctrl, int k) {
  __shared__ u32 b0[2048], b1[2048];
  u32 t = threadIdx.x;
  b0[t] = hist[t]; b0[t + 1024] = hist[t + 1024];
  __syncthreads();
  u32* src = b0; u32* dst = b1;
  for (u32 off = 1; off < 2048; off <<= 1) {
    for (u32 i = t; i < 2048; i += 1024) {
      u32 v = src[i];
      if (i + off < 2048) v += src[i + off];
      dst[i] = v;
    }
    __syncthreads();
    u32* tmp = src; src = dst; dst = tmp;
  }
  u32 K = (u32)k;
  for (u32 i = t; i < 2048; i += 1024) {
    u32 cum = src[i];
    u32 nxt = (i + 1 < 2048) ? src[i + 1] : 0u;
    if (cum >= K && nxt < K) {
      ctrl[0] = i;
      ctrl[1] = nxt;
      ctrl[2] = K - nxt;
    }
  }
}

// ---------------- Pass 3: fused output pass + compaction ----------
__global__ void k_main(const float4* __restrict__ g, const float4* __restrict__ r,
                       const float* __restrict__ momp,
                       float4* __restrict__ res4, float4* __restrict__ sp4,
                       u32* __restrict__ ctrl, u64* __restrict__ cand,
                       u64* __restrict__ memb, int n4) {
  float m = *momp;
  u32 B = ctrl[0];
  int stride = gridDim.x * blockDim.x;
  for (int i = blockIdx.x * blockDim.x + threadIdx.x; i < n4; i += stride) {
    float4 a = g[i]; float4 b = r[i];
    float4 ro, so;
    u32 base = (u32)i * 4u;
#define PROC(X, J, RO, SO) { \
    float c = a.X + b.X; \
    u32 cb = __float_as_uint(c); \
    u32 u = cb & 0x7fffffffu; \
    u32 bin = u >> 20; \
    float rv = b.X + m * a.X; float sv = 0.f; \
    if (bin >= B) { \
      u32 idx = base + J; \
      if (bin > B) { \
        rv = 0.f; sv = c; \
        u32 slot = atomicAdd(&ctrl[4], 1u); \
        if (slot < MEMB_MAX) memb[slot] = ((u64)fkey32(cb) << 32) | (u64)idx; \
      } else { \
        u32 slot = atomicAdd(&ctrl[3], 1u); \
        if (slot < CAND_MAX) cand[slot] = ((u64)u << 32) | (u64)(idx | (cb & 0x80000000u)); \
      } \
    } \
    RO = rv; SO = sv; }
    PROC(x, 0u, ro.x, so.x)
    PROC(y, 1u, ro.y, so.y)
    PROC(z, 2u, ro.z, so.z)
    PROC(w, 3u, ro.w, so.w)
#undef PROC
    res4[i] = ro;
    sp4[i] = so;
  }
}

// ---------------- Refine: exact 32-bit threshold + tie cutoff (single block) --------
__global__ void __launch_bounds__(1024) k_refine(u32* __restrict__ ctrl,
                                                 const u64* __restrict__ cand) {
  __shared__ u32 h[1024], h2[1024];
  __shared__ u32 tie[2048];
  __shared__ u32 res[4];
  __shared__ u32 nt;
  u32 t = threadIdx.x;
  u32 nc = ctrl[3]; if (nc > CAND_MAX) nc = CAND_MAX;
  u32 r = ctrl[2];
  u32 B12 = ctrl[0];

  // level 1: bits 19..10
  h[t] = 0; if (t == 0) nt = 0;
  __syncthreads();
  for (u32 i = t; i < nc; i += 1024) {
    u32 u = (u32)(cand[i] >> 32);
    atomicAdd(&h[(u >> 10) & 1023u], 1u);
  }
  __syncthreads();
  u32* src = h; u32* dst = h2;
  for (u32 off = 1; off < 1024; off <<= 1) {
    u32 v = src[t] + ((t + off < 1024) ? src[t + off] : 0u);
    dst[t] = v;
    __syncthreads();
    u32* tmp = src; src = dst; dst = tmp;
  }
  {
    u32 cum = src[t];
    u32 nxt = (t + 1 < 1024) ? src[t + 1] : 0u;
    if (cum >= r && nxt < r) { res[0] = t; res[1] = nxt; }
  }
  __syncthreads();
  u32 B1 = res[0];
  u32 r1 = r - res[1];
  __syncthreads();

  // level 2: bits 9..0 among mid == B1
  h[t] = 0; h2[t] = 0;
  __syncthreads();
  for (u32 i = t; i < nc; i += 1024) {
    u32 u = (u32)(cand[i] >> 32);
    if (((u >> 10) & 1023u) == B1) atomicAdd(&h[u & 1023u], 1u);
  }
  __syncthreads();
  src = h; dst = h2;
  for (u32 off = 1; off < 1024; off <<= 1) {
    u32 v = src[t] + ((t + off < 1024) ? src[t + off] : 0u);
    dst[t] = v;
    __syncthreads();
    u32* tmp = src; src = dst; dst = tmp;
  }
  {
    u32 cum = src[t];
    u32 nxt = (t + 1 < 1024) ? src[t + 1] : 0u;
    if (cum >= r1 && nxt < r1) { res[2] = t; res[3] = nxt; }
  }
  __syncthreads();
  u32 B2 = res[2];
  u32 r2 = r1 - res[3];
  u32 T = (B12 << 20) | (B1 << 10) | B2;
  __syncthreads();

  // collect indices with u == T, pick the r2-th smallest as cutoff
  for (u32 i = t; i < nc; i += 1024) {
    u64 e = cand[i];
    if ((u32)(e >> 32) == T) {
      u32 p = atomicAdd(&nt, 1u);
      if (p < 2048u) tie[p] = (u32)e & 0x7fffffffu;
    }
  }
  __syncthreads();
  u32 ntc = nt; if (ntc > 2048u) ntc = 2048u;
  for (u32 i = t; i < ntc; i += 1024) {
    u32 ti = tie[i];
    u32 rank = 0;
    for (u32 j = 0; j < ntc; j++) rank += (tie[j] < ti) ? 1u : 0u;
    if (rank == r2 - 1u) ctrl[6] = ti;
  }
  if (t == 0) ctrl[5] = T;
}

// ---------------- Patch chosen boundary candidates ----------
__global__ void k_patch(u32* __restrict__ ctrl, const u64* __restrict__ cand,
                        float* __restrict__ res_out, float* __restrict__ sp_out,
                        u64* __restrict__ memb) {
  u32 nc = ctrl[3]; if (nc > CAND_MAX) nc = CAND_MAX;
  u32 T = ctrl[5];
  u32 cut = ctrl[6];
  u32 stride = gridDim.x * blockDim.x;
  for (u32 i = blockIdx.x * blockDim.x + threadIdx.x; i < nc; i += stride) {
    u64 e = cand[i];
    u32 u = (u32)(e >> 32);
    u32 low = (u32)e;
    u32 idx = low & 0x7fffffffu;
    bool chosen = (u > T) || (u == T && idx <= cut);
    if (chosen) {
      u32 cb = u | (low & 0x80000000u);
      res_out[idx] = 0.f;
      sp_out[idx] = __uint_as_float(cb);
      u32 slot = atomicAdd(&ctrl[4], 1u);
      if (slot < MEMB_MAX) memb[slot] = ((u64)fkey32(cb) << 32) | (u64)idx;
    }
  }
}

// ---------------- Pad member list to SORT_N with +inf keys ----------
__global__ void k_pad(u64* __restrict__ memb, int k) {
  int i = blockIdx.x * blockDim.x + threadIdx.x;
  if (i >= k && i < (int)SORT_N) memb[i] = ~0ull;
}

// ---------------- Bitonic sort (ascending) on 65536 u64 keys ----------
__global__ void __launch_bounds__(1024) k_blocal(u64* __restrict__ d) {
  __shared__ u64 s[8192];
  u32 base = blockIdx.x * 8192u;
  for (u32 i = threadIdx.x; i < 8192u; i += blockDim.x) s[i] = d[base + i];
  __syncthreads();
  for (u32 kk = 2; kk <= 8192u; kk <<= 1) {
    for (u32 jj = kk >> 1; jj > 0; jj >>= 1) {
      for (u32 t = threadIdx.x; t < 4096u; t += blockDim.x) {
        u32 i = 2u * t - (t & (jj - 1u));
        u32 l = i + jj;
        u64 x = s[i], y = s[l];
        bool up = (((base + i) & kk) == 0u);
        bool sw = up ? (x > y) : (y > x);
        if (sw) { s[i] = y; s[l] = x; }
      }
      __syncthreads();
    }
  }
  for (u32 i = threadIdx.x; i < 8192u; i += blockDim.x) d[base + i] = s[i];
}

__global__ void __launch_bounds__(1024) k_bstep(u64* __restrict__ d, u32 kk, u32 jj) {
  u32 t = blockIdx.x * blockDim.x + threadIdx.x;
  u32 i = 2u * t - (t & (jj - 1u));
  u32 l = i + jj;
  u64 x = d[i], y = d[l];
  bool up = ((i & kk) == 0u);
  bool sw = up ? (x > y) : (y > x);
  if (sw) { d[i] = y; d[l] = x; }
}

__global__ void __launch_bounds__(1024) k_bmerge(u64* __restrict__ d, u32 kk) {
  __shared__ u64 s[8192];
  u32 base = blockIdx.x * 8192u;
  for (u32 i = threadIdx.x; i < 8192u; i += blockDim.x) s[i] = d[base + i];
  __syncthreads();
  for (u32 jj = 4096u; jj > 0; jj >>= 1) {
    for (u32 t = threadIdx.x; t < 4096u; t += blockDim.x) {
      u32 i = 2u * t - (t & (jj - 1u));
      u32 l = i + jj;
      u64 x = s[i], y = s[l];
      bool up = (((base + i) & kk) == 0u);
      bool sw = up ? (x > y) : (y > x);
      if (sw) { s[i] = y; s[l] = x; }
    }
    __syncthreads();
  }
  for (u32 i = threadIdx.x; i < 8192u; i += blockDim.x) d[base + i] = s[i];
}

// ---------------- Emit indices (as float) and values ----------
__global__ void k_write(const u64* __restrict__ memb, float* __restrict__ out, int k) {
  int i = blockIdx.x * blockDim.x + threadIdx.x;
  if (i >= k) return;
  u64 e = memb[i];
  u32 idx = (u32)e;
  u32 h = (u32)(e >> 32);
  u32 fb = (h & 0x80000000u) ? (h ^ 0x80000000u) : ~h;
  out[i] = (float)idx;
  out[k + i] = __uint_as_float(fb);
}

extern "C" void kernel_launch(void* const* d_in, const int* in_sizes, int n_in,
                              void* d_out, int out_size, void* d_ws, size_t ws_size,
                              hipStream_t stream) {
  const float* g   = (const float*)d_in[0];
  const float* r   = (const float*)d_in[1];
  const float* mom = (const float*)d_in[2];
  int n = in_sizes[0];
  int k = (out_size - 2 * n) / 2;   // host-side recovery of k
  int n4 = n / 4;

  float* out = (float*)d_out;
  float* res_out = out + 2 * (size_t)k;
  float* sp_out  = res_out + (size_t)n;

  unsigned char* ws = (unsigned char*)d_ws;
  u32* hist = (u32*)ws;                                   // 2048 * 4 = 8 KB
  u32* ctrl = (u32*)(ws + 8192);                          // 32 words
  u64* cand = (u64*)(ws + 16384);                         // 1 MB
  u64* memb = (u64*)(ws + 16384 + (size_t)CAND_MAX * 8);  // 512 KB

  hipMemsetAsync(ws, 0, 16384, stream);

  k_hist<<<2048, 256, 0, stream>>>((const float4*)g, (const float4*)r, n4, hist);
  k_scan<<<1, 1024, 0, stream>>>(hist, ctrl, k);
  k_main<<<2048, 256, 0, stream>>>((const float4*)g, (const float4*)r, mom,
                                   (float4*)res_out, (float4*)sp_out,
                                   ctrl, cand, memb, n4);
  k_refine<<<1, 1024, 0, stream>>>(ctrl, cand);
  k_patch<<<256, 256, 0, stream>>>(ctrl, cand, res_out, sp_out, memb);
  k_pad<<<SORT_N / 256, 256, 0, stream>>>(memb, k);

  k_blocal<<<SORT_N / 8192, 1024, 0, stream>>>(memb);
  for (u32 kk = 16384u; kk <= SORT_N; kk <<= 1) {
    for (u32 jj = kk >> 1; jj >= 8192u; jj >>= 1)
      k_bstep<<<SORT_N / 2048, 1024, 0, stream>>>(memb, kk, jj);
    k_bmerge<<<SORT_N / 8192, 1024, 0, stream>>>(memb, kk);
  }

  k_write<<<(SORT_N + 255) / 256, 256, 0, stream>>>(memb, out, k);
}